// Round 1
// baseline (105.267 us; speedup 1.0000x reference)
//
#include <hip/hip_runtime.h>
#include <math.h>

#define BB 16
#define SS 8192
#define DD 512
#define HH 512
#define NEG_INF (-1e18f)

__device__ __forceinline__ float dot8(float4 a0, float4 a1, float4 b0, float4 b1) {
  return a0.x*b0.x + a0.y*b0.y + a0.z*b0.z + a0.w*b0.w
       + a1.x*b1.x + a1.y*b1.y + a1.z*b1.z + a1.w*b1.w;
}

__device__ __forceinline__ float wave_sum64(float p) {
  #pragma unroll
  for (int off = 32; off; off >>= 1) p += __shfl_xor(p, off, 64);
  return p;
}

// K0a: 80 blocks x 256 threads.
// blocks [0,64): tpart[b][h] = wout[h]*(dot(Wq[h],query[b]) + bq[h] + bk[h])
// blocks [64,80): vpart[j][d] = sum_{h in j-th 32-chunk} wout[h]*Wk[h][d]
__global__ void k_prep(const float* __restrict__ query, const float* __restrict__ Wq,
                       const float* __restrict__ bq, const float* __restrict__ Wk,
                       const float* __restrict__ bk, const float* __restrict__ wout,
                       float* __restrict__ tpart, float* __restrict__ vpart)
{
  int blk = blockIdx.x;
  int tid = threadIdx.x;
  if (blk < 64) {
    int b = blk >> 2, hc = blk & 3;
    int wave = tid >> 6, lane = tid & 63;
    const float4* q4 = (const float4*)(query + (size_t)b * DD);
    float4 q0 = q4[lane], q1 = q4[64 + lane];
    for (int j = 0; j < 32; ++j) {
      int h = hc * 128 + wave * 32 + j;
      const float4* wr = (const float4*)(Wq + (size_t)h * DD);
      float4 w0 = wr[lane], w1 = wr[64 + lane];
      float p = wave_sum64(dot8(q0, q1, w0, w1));
      if (lane == 0) tpart[b * HH + h] = wout[h] * (p + bq[h] + bk[h]);
    }
  } else {
    int j = blk - 64;
    float a0 = 0.f, a1 = 0.f;
    for (int h = j * 32; h < j * 32 + 32; ++h) {
      float w = wout[h];
      a0 += w * Wk[(size_t)h * DD + tid];
      a1 += w * Wk[(size_t)h * DD + tid + 256];
    }
    vpart[j * DD + tid] = a0;
    vpart[j * DD + tid + 256] = a1;
  }
}

// K0b: 1 block x 512 threads. v[d] = sum_j vpart[j][d]; qconst[b] = sum_h tpart[b][h]
__global__ void k_reduce(const float* __restrict__ tpart, const float* __restrict__ vpart,
                         float* __restrict__ v, float* __restrict__ qconst)
{
  int tid = threadIdx.x;  // 512
  float a = 0.f;
  #pragma unroll
  for (int j = 0; j < 16; ++j) a += vpart[j * DD + tid];
  v[tid] = a;
  // qconst: 16 b's x 32 threads each (within half-wave groups)
  int b = tid >> 5, t = tid & 31;
  float q = 0.f;
  #pragma unroll
  for (int k = 0; k < 16; ++k) q += tpart[b * HH + t + 32 * k];
  #pragma unroll
  for (int off = 16; off; off >>= 1) q += __shfl_xor(q, off, 64);
  if (t == 0) qconst[b] = q;
}

// K1: main streaming pass. grid = B*bpb blocks x 256 threads (4 waves).
// Each wave: rows s = s0 + wave + 4*i. Lane owns d = [4*lane,4*lane+4) and [256+4*lane, +4).
// Computes score = key.v + qconst, writes attn_weight, online softmax accum of u = sum p*key.
__global__ __launch_bounds__(256) void k_score(
    const float* __restrict__ key, const int* __restrict__ mask,
    const float* __restrict__ v, const float* __restrict__ qconst,
    float* __restrict__ scores, float* __restrict__ partials, int bpb)
{
  int blk = blockIdx.x;
  int b = blk / bpb;
  int pb = blk % bpb;
  int rows = SS / bpb;
  int s0 = pb * rows;
  int wave = threadIdx.x >> 6;
  int lane = threadIdx.x & 63;

  const float4* vv = (const float4*)v;
  float4 v0 = vv[lane];
  float4 v1 = vv[64 + lane];
  float qc = qconst[b];
  const float4* keyb = (const float4*)(key + (size_t)b * SS * DD);

  float m = -INFINITY;
  float l = 0.f;
  float4 u0 = {0.f,0.f,0.f,0.f}, u1 = {0.f,0.f,0.f,0.f};

  int nit = rows >> 2;  // 4 waves
  int s = s0 + wave;
  const float4* rp = keyb + (size_t)s * (DD / 4);
  float4 k0 = rp[lane];
  float4 k1 = rp[64 + lane];
  int mk = mask[b * SS + s];

  for (int i = 0; i < nit; ++i) {
    float4 kn0 = k0, kn1 = k1;
    int mkn = 0;
    int sn = s + 4;
    if (i + 1 < nit) {
      const float4* rn = keyb + (size_t)sn * (DD / 4);
      kn0 = rn[lane];
      kn1 = rn[64 + lane];
      mkn = mask[b * SS + sn];
    }
    float p = wave_sum64(dot8(k0, k1, v0, v1));
    float score = mk ? NEG_INF : (p + qc);
    if (lane == 0) scores[b * SS + s] = score;
    // online softmax update (branch is wave-uniform: score uniform after reduce)
    if (score > m) {
      float scale = expf(m - score);  // expf(-inf)=0 on first row
      l *= scale;
      u0.x *= scale; u0.y *= scale; u0.z *= scale; u0.w *= scale;
      u1.x *= scale; u1.y *= scale; u1.z *= scale; u1.w *= scale;
      m = score;
    }
    float e = expf(score - m);
    l += e;
    u0.x += e * k0.x; u0.y += e * k0.y; u0.z += e * k0.z; u0.w += e * k0.w;
    u1.x += e * k1.x; u1.y += e * k1.y; u1.z += e * k1.z; u1.w += e * k1.w;
    k0 = kn0; k1 = kn1; mk = mkn; s = sn;
  }

  // block combine across 4 waves
  __shared__ float ls_m[4], ls_l[4];
  __shared__ __align__(16) float ls_u[4][DD];
  ls_u[wave][4 * lane + 0] = u0.x; ls_u[wave][4 * lane + 1] = u0.y;
  ls_u[wave][4 * lane + 2] = u0.z; ls_u[wave][4 * lane + 3] = u0.w;
  ls_u[wave][256 + 4 * lane + 0] = u1.x; ls_u[wave][256 + 4 * lane + 1] = u1.y;
  ls_u[wave][256 + 4 * lane + 2] = u1.z; ls_u[wave][256 + 4 * lane + 3] = u1.w;
  if (lane == 0) { ls_m[wave] = m; ls_l[wave] = l; }
  __syncthreads();

  float M = fmaxf(fmaxf(ls_m[0], ls_m[1]), fmaxf(ls_m[2], ls_m[3]));
  float f0 = expf(ls_m[0] - M), f1 = expf(ls_m[1] - M);
  float f2 = expf(ls_m[2] - M), f3 = expf(ls_m[3] - M);
  int d = threadIdx.x;  // 0..255
  float ua = ls_u[0][d] * f0 + ls_u[1][d] * f1 + ls_u[2][d] * f2 + ls_u[3][d] * f3;
  float ub = ls_u[0][d + 256] * f0 + ls_u[1][d + 256] * f1
           + ls_u[2][d + 256] * f2 + ls_u[3][d + 256] * f3;
  float* part = partials + (size_t)(b * bpb + pb) * (DD + 2);
  part[2 + d] = ua;
  part[2 + 256 + d] = ub;
  if (threadIdx.x == 0) {
    part[0] = M;
    part[1] = ls_l[0] * f0 + ls_l[1] * f1 + ls_l[2] * f2 + ls_l[3] * f3;
  }
}

// K2: grid = B*8 blocks x 256 threads. Combine partials -> ubar (LDS), then
// attn[b][h] = dot(Wk[h], ubar) + bk[h] for 64 h per block (wave-per-h dots).
__global__ __launch_bounds__(256) void k_out(
    const float* __restrict__ Wk, const float* __restrict__ bk,
    const float* __restrict__ partials, float* __restrict__ attn, int bpb)
{
  int b = blockIdx.x >> 3;
  int hc = blockIdx.x & 7;
  int tid = threadIdx.x;
  __shared__ __align__(16) float ubar[DD];

  const float* pb_ = partials + (size_t)b * bpb * (DD + 2);
  float M = -INFINITY;
  for (int p = 0; p < bpb; ++p) M = fmaxf(M, pb_[p * (DD + 2)]);
  float denom = 0.f;
  for (int p = 0; p < bpb; ++p) denom += pb_[p * (DD + 2) + 1] * expf(pb_[p * (DD + 2)] - M);
  float ua = 0.f, ub = 0.f;
  for (int p = 0; p < bpb; ++p) {
    float f = expf(pb_[p * (DD + 2)] - M);
    ua += pb_[p * (DD + 2) + 2 + tid] * f;
    ub += pb_[p * (DD + 2) + 2 + 256 + tid] * f;
  }
  ubar[tid] = ua / denom;
  ubar[tid + 256] = ub / denom;
  __syncthreads();

  int wave = tid >> 6, lane = tid & 63;
  const float4* ub4 = (const float4*)ubar;
  float4 x0 = ub4[lane], x1 = ub4[64 + lane];
  for (int j = 0; j < 16; ++j) {
    int h = hc * 64 + wave * 16 + j;
    const float4* wr = (const float4*)(Wk + (size_t)h * DD);
    float4 w0 = wr[lane], w1 = wr[64 + lane];
    float p = wave_sum64(dot8(w0, w1, x0, x1));
    if (lane == 0) attn[b * HH + h] = p + bk[h];
  }
}

extern "C" void kernel_launch(void* const* d_in, const int* in_sizes, int n_in,
                              void* d_out, int out_size, void* d_ws, size_t ws_size,
                              hipStream_t stream) {
  const float* query = (const float*)d_in[0];
  const float* key   = (const float*)d_in[1];
  const int*   mask  = (const int*)d_in[2];
  const float* Wq    = (const float*)d_in[3];
  const float* bq    = (const float*)d_in[4];
  const float* Wk    = (const float*)d_in[5];
  const float* bk    = (const float*)d_in[6];
  const float* wout  = (const float*)d_in[7];

  float* out    = (float*)d_out;
  float* attn   = out;                 // (B, H)
  float* scores = out + BB * HH;       // (B, S)
  float* ws     = (float*)d_ws;

  // ws layout (floats)
  const size_t off_v     = 0;                      // 512
  const size_t off_qc    = 512;                    // 16
  const size_t off_vpart = 528;                    // 16*512
  const size_t off_tpart = off_vpart + 16 * DD;    // 16*512
  const size_t off_part  = off_tpart + BB * HH;    // B*bpb*(D+2)

  int bpb = 32;
  while (bpb > 1 && (off_part + (size_t)BB * bpb * (DD + 2)) * 4 > ws_size) bpb >>= 1;

  k_prep<<<dim3(80), dim3(256), 0, stream>>>(query, Wq, bq, Wk, bk, wout,
                                             ws + off_tpart, ws + off_vpart);
  k_reduce<<<dim3(1), dim3(512), 0, stream>>>(ws + off_tpart, ws + off_vpart,
                                              ws + off_v, ws + off_qc);
  k_score<<<dim3(BB * bpb), dim3(256), 0, stream>>>(key, mask, ws + off_v, ws + off_qc,
                                                    scores, ws + off_part, bpb);
  k_out<<<dim3(BB * 8), dim3(256), 0, stream>>>(Wk, bk, ws + off_part, attn, bpb);
}

// Round 2
// 82.579 us; speedup vs baseline: 1.2747x; 1.2747x over previous
//
#include <hip/hip_runtime.h>
#include <math.h>

#define BB 16
#define SS 8192
#define DD 512
#define HH 512
#define NEG_INF (-1e18f)
#define BPB 64   // score-blocks per batch: 16*64 = 1024 blocks = 4 per CU

__device__ __forceinline__ float dot8(float4 a0, float4 a1, float4 b0, float4 b1) {
  return a0.x*b0.x + a0.y*b0.y + a0.z*b0.z + a0.w*b0.w
       + a1.x*b1.x + a1.y*b1.y + a1.z*b1.z + a1.w*b1.w;
}

__device__ __forceinline__ float wave_sum64(float p) {
  #pragma unroll
  for (int off = 32; off; off >>= 1) p += __shfl_xor(p, off, 64);
  return p;
}

// K0a: 80 blocks x 256 threads.
// blocks [0,64): tpart[b][h] = wout[h]*(dot(Wq[h],query[b]) + bq[h] + bk[h])
// blocks [64,80): vpart[j][d] = sum_{h in j-th 32-chunk} wout[h]*Wk[h][d]
__global__ void k_prep(const float* __restrict__ query, const float* __restrict__ Wq,
                       const float* __restrict__ bq, const float* __restrict__ Wk,
                       const float* __restrict__ bk, const float* __restrict__ wout,
                       float* __restrict__ tpart, float* __restrict__ vpart)
{
  int blk = blockIdx.x;
  int tid = threadIdx.x;
  if (blk < 64) {
    int b = blk >> 2, hc = blk & 3;
    int wave = tid >> 6, lane = tid & 63;
    const float4* q4 = (const float4*)(query + (size_t)b * DD);
    float4 q0 = q4[lane], q1 = q4[64 + lane];
    for (int j = 0; j < 32; ++j) {
      int h = hc * 128 + wave * 32 + j;
      const float4* wr = (const float4*)(Wq + (size_t)h * DD);
      float4 w0 = wr[lane], w1 = wr[64 + lane];
      float p = wave_sum64(dot8(q0, q1, w0, w1));
      if (lane == 0) tpart[b * HH + h] = wout[h] * (p + bq[h] + bk[h]);
    }
  } else {
    int j = blk - 64;
    float a0 = 0.f, a1 = 0.f;
    for (int h = j * 32; h < j * 32 + 32; ++h) {
      float w = wout[h];
      a0 += w * Wk[(size_t)h * DD + tid];
      a1 += w * Wk[(size_t)h * DD + tid + 256];
    }
    vpart[j * DD + tid] = a0;
    vpart[j * DD + tid + 256] = a1;
  }
}

// K0b: 1 block x 512 threads. v[d] = sum_j vpart[j][d]; qconst[b] = sum_h tpart[b][h]
__global__ void k_reduce(const float* __restrict__ tpart, const float* __restrict__ vpart,
                         float* __restrict__ v, float* __restrict__ qconst)
{
  int tid = threadIdx.x;  // 512
  float a = 0.f;
  #pragma unroll
  for (int j = 0; j < 16; ++j) a += vpart[j * DD + tid];
  v[tid] = a;
  int b = tid >> 5, t = tid & 31;
  float q = 0.f;
  #pragma unroll
  for (int k = 0; k < 16; ++k) q += tpart[b * HH + t + 32 * k];
  #pragma unroll
  for (int off = 16; off; off >>= 1) q += __shfl_xor(q, off, 64);
  if (t == 0) qconst[b] = q;
}

// K1: main streaming pass. grid = B*BPB blocks x 256 threads (4 waves).
// Each wave handles 2 consecutive rows per iteration (independent reduce chains),
// stride 8 rows; prefetch next pair one iteration ahead.
__global__ __launch_bounds__(256) void k_score(
    const float* __restrict__ key, const int* __restrict__ mask,
    const float* __restrict__ v, const float* __restrict__ qconst,
    float* __restrict__ scores, float* __restrict__ partials)
{
  int blk = blockIdx.x;
  int b = blk / BPB;
  int pb = blk % BPB;
  const int rows = SS / BPB;       // 128
  int s0 = pb * rows;
  int wave = threadIdx.x >> 6;
  int lane = threadIdx.x & 63;

  const float4* vv = (const float4*)v;
  float4 v0 = vv[lane], v1 = vv[64 + lane];
  float qc = qconst[b];
  const float4* keyb = (const float4*)(key + (size_t)b * SS * DD);
  const int* maskb = mask + b * SS;

  float m = -INFINITY, l = 0.f;
  float4 u0 = {0.f,0.f,0.f,0.f}, u1 = {0.f,0.f,0.f,0.f};

  const int nit = rows / 8;  // 16 iterations, 8 rows/block/iter
  int s = s0 + wave * 2;

  const float4* rp0 = keyb + (size_t)s * (DD / 4);
  const float4* rp1 = keyb + (size_t)(s + 1) * (DD / 4);
  float4 a0 = rp0[lane], a1 = rp0[64 + lane];
  float4 c0 = rp1[lane], c1 = rp1[64 + lane];
  int ma = maskb[s], mc = maskb[s + 1];

  for (int i = 0; i < nit; ++i) {
    float4 na0 = a0, na1 = a1, nc0 = c0, nc1 = c1;
    int nma = 0, nmc = 0;
    if (i + 1 < nit) {
      const float4* q0 = keyb + (size_t)(s + 8) * (DD / 4);
      const float4* q1 = keyb + (size_t)(s + 9) * (DD / 4);
      na0 = q0[lane]; na1 = q0[64 + lane];
      nc0 = q1[lane]; nc1 = q1[64 + lane];
      nma = maskb[s + 8]; nmc = maskb[s + 9];
    }
    float pa = wave_sum64(dot8(a0, a1, v0, v1));
    float pc = wave_sum64(dot8(c0, c1, v0, v1));
    float sca = ma ? NEG_INF : (pa + qc);
    float scc = mc ? NEG_INF : (pc + qc);
    if (lane == 0) {
      float2 st; st.x = sca; st.y = scc;
      *(float2*)(scores + (size_t)b * SS + s) = st;
    }
    float mn = fmaxf(m, fmaxf(sca, scc));
    if (mn > m) {  // wave-uniform branch
      float sc = __expf(m - mn);  // exp(-inf)=0 on first real row
      l *= sc;
      u0.x *= sc; u0.y *= sc; u0.z *= sc; u0.w *= sc;
      u1.x *= sc; u1.y *= sc; u1.z *= sc; u1.w *= sc;
      m = mn;
    }
    float ea = __expf(sca - m), ec = __expf(scc - m);
    l += ea + ec;
    u0.x += ea * a0.x + ec * c0.x; u0.y += ea * a0.y + ec * c0.y;
    u0.z += ea * a0.z + ec * c0.z; u0.w += ea * a0.w + ec * c0.w;
    u1.x += ea * a1.x + ec * c1.x; u1.y += ea * a1.y + ec * c1.y;
    u1.z += ea * a1.z + ec * c1.z; u1.w += ea * a1.w + ec * c1.w;
    a0 = na0; a1 = na1; c0 = nc0; c1 = nc1; ma = nma; mc = nmc; s += 8;
  }

  // block combine across 4 waves
  __shared__ float ls_m[4], ls_l[4];
  __shared__ __align__(16) float ls_u[4][DD];
  ls_u[wave][4 * lane + 0] = u0.x; ls_u[wave][4 * lane + 1] = u0.y;
  ls_u[wave][4 * lane + 2] = u0.z; ls_u[wave][4 * lane + 3] = u0.w;
  ls_u[wave][256 + 4 * lane + 0] = u1.x; ls_u[wave][256 + 4 * lane + 1] = u1.y;
  ls_u[wave][256 + 4 * lane + 2] = u1.z; ls_u[wave][256 + 4 * lane + 3] = u1.w;
  if (lane == 0) { ls_m[wave] = m; ls_l[wave] = l; }
  __syncthreads();

  float M = fmaxf(fmaxf(ls_m[0], ls_m[1]), fmaxf(ls_m[2], ls_m[3]));
  float f0 = __expf(ls_m[0] - M), f1 = __expf(ls_m[1] - M);
  float f2 = __expf(ls_m[2] - M), f3 = __expf(ls_m[3] - M);
  int d = threadIdx.x;  // 0..255
  float ua = ls_u[0][d] * f0 + ls_u[1][d] * f1 + ls_u[2][d] * f2 + ls_u[3][d] * f3;
  float ub = ls_u[0][d + 256] * f0 + ls_u[1][d + 256] * f1
           + ls_u[2][d + 256] * f2 + ls_u[3][d + 256] * f3;
  float* part = partials + (size_t)(b * BPB + pb) * (DD + 2);
  part[2 + d] = ua;
  part[2 + 256 + d] = ub;
  if (threadIdx.x == 0) {
    part[0] = M;
    part[1] = ls_l[0] * f0 + ls_l[1] * f1 + ls_l[2] * f2 + ls_l[3] * f3;
  }
}

// K2: grid = B*8 blocks x 256 threads. Combine partials -> ubar (LDS), then
// attn[b][h] = dot(Wk[h], ubar) + bk[h] for 64 h per block (wave-per-h dots).
__global__ __launch_bounds__(256) void k_out(
    const float* __restrict__ Wk, const float* __restrict__ bk,
    const float* __restrict__ partials, float* __restrict__ attn)
{
  int b = blockIdx.x >> 3;
  int hc = blockIdx.x & 7;
  int tid = threadIdx.x;
  __shared__ __align__(16) float ubar[DD];
  __shared__ float fsh[BPB];
  __shared__ float dsh;

  const float* pbase = partials + (size_t)b * BPB * (DD + 2);

  // wave 0: lane p owns partial p (BPB=64): parallel max + weight + denom
  if (tid < 64) {
    float mp = pbase[tid * (DD + 2)];
    float lp = pbase[tid * (DD + 2) + 1];
    float M = mp;
    #pragma unroll
    for (int off = 32; off; off >>= 1) M = fmaxf(M, __shfl_xor(M, off, 64));
    float f = __expf(mp - M);
    fsh[tid] = f;
    float dn = wave_sum64(lp * f);
    if (tid == 0) dsh = dn;
  }
  __syncthreads();

  float denom = dsh;
  float ua = 0.f, ub = 0.f;
  #pragma unroll 8
  for (int p = 0; p < BPB; ++p) {
    float f = fsh[p];
    ua += pbase[p * (DD + 2) + 2 + tid] * f;
    ub += pbase[p * (DD + 2) + 2 + 256 + tid] * f;
  }
  ubar[tid] = ua / denom;
  ubar[tid + 256] = ub / denom;
  __syncthreads();

  int wave = tid >> 6, lane = tid & 63;
  const float4* ub4 = (const float4*)ubar;
  float4 x0 = ub4[lane], x1 = ub4[64 + lane];
  for (int j = 0; j < 16; ++j) {
    int h = hc * 64 + wave * 16 + j;
    const float4* wr = (const float4*)(Wk + (size_t)h * DD);
    float4 w0 = wr[lane], w1 = wr[64 + lane];
    float p = wave_sum64(dot8(w0, w1, x0, x1));
    if (lane == 0) attn[b * HH + h] = p + bk[h];
  }
}

extern "C" void kernel_launch(void* const* d_in, const int* in_sizes, int n_in,
                              void* d_out, int out_size, void* d_ws, size_t ws_size,
                              hipStream_t stream) {
  const float* query = (const float*)d_in[0];
  const float* key   = (const float*)d_in[1];
  const int*   mask  = (const int*)d_in[2];
  const float* Wq    = (const float*)d_in[3];
  const float* bq    = (const float*)d_in[4];
  const float* Wk    = (const float*)d_in[5];
  const float* bk    = (const float*)d_in[6];
  const float* wout  = (const float*)d_in[7];

  float* out    = (float*)d_out;
  float* attn   = out;                 // (B, H)
  float* scores = out + BB * HH;       // (B, S)
  float* ws     = (float*)d_ws;

  // ws layout (floats)
  const size_t off_v     = 0;                      // 512
  const size_t off_qc    = 512;                    // 16
  const size_t off_vpart = 528;                    // 16*512
  const size_t off_tpart = off_vpart + 16 * DD;    // 16*512
  const size_t off_part  = off_tpart + BB * HH;    // B*BPB*(D+2) ~ 2.1 MB

  k_prep<<<dim3(80), dim3(256), 0, stream>>>(query, Wq, bq, Wk, bk, wout,
                                             ws + off_tpart, ws + off_vpart);
  k_reduce<<<dim3(1), dim3(512), 0, stream>>>(ws + off_tpart, ws + off_vpart,
                                              ws + off_v, ws + off_qc);
  k_score<<<dim3(BB * BPB), dim3(256), 0, stream>>>(key, mask, ws + off_v, ws + off_qc,
                                                    scores, ws + off_part);
  k_out<<<dim3(BB * 8), dim3(256), 0, stream>>>(Wk, bk, ws + off_part, attn);
}

// Round 3
// 69.089 us; speedup vs baseline: 1.5236x; 1.1953x over previous
//
#include <hip/hip_runtime.h>
#include <math.h>

#define BB 16
#define SS 8192
#define DD 512
#define HH 512
#define NEG_INF (-1e18f)
#define BPB 64   // score-blocks per batch: 16*64 = 1024 blocks = 4 per CU

__device__ __forceinline__ float dot8(float4 a0, float4 a1, float4 b0, float4 b1) {
  return a0.x*b0.x + a0.y*b0.y + a0.z*b0.z + a0.w*b0.w
       + a1.x*b1.x + a1.y*b1.y + a1.z*b1.z + a1.w*b1.w;
}

__device__ __forceinline__ float wave_sum64(float p) {
  #pragma unroll
  for (int off = 32; off; off >>= 1) p += __shfl_xor(p, off, 64);
  return p;
}

// K0a: 32 blocks x 256 threads. blocks [0,16): vpart[j][d] += wout[h]*Wk[h][d]
// over the j-th 32-h chunk; blocks [16,32): same for Wq -> wpart.
__global__ __launch_bounds__(256) void k_gemv(
    const float* __restrict__ Wq, const float* __restrict__ Wk,
    const float* __restrict__ wout, float* __restrict__ wpart,
    float* __restrict__ vpart)
{
  int blk = blockIdx.x;
  int tid = threadIdx.x;
  int j = blk & 15;
  const float* W = (blk < 16) ? Wk : Wq;
  float* outp = (blk < 16) ? vpart : wpart;
  float a0 = 0.f, a1 = 0.f;
  #pragma unroll 8
  for (int h = j * 32; h < j * 32 + 32; ++h) {
    float w = wout[h];
    a0 += w * W[(size_t)h * DD + tid];
    a1 += w * W[(size_t)h * DD + tid + 256];
  }
  outp[j * DD + tid] = a0;
  outp[j * DD + tid + 256] = a1;
}

// K0b: 1 block x 512 threads.
// v[d] = sum_j vpart[j][d]; w2[d] = sum_j wpart[j][d];
// c0 = sum_h wout[h]*(bq[h]+bk[h]); qconst[b] = query[b].w2 + c0
__global__ __launch_bounds__(512) void k_fin(
    const float* __restrict__ query, const float* __restrict__ vpart,
    const float* __restrict__ wpart, const float* __restrict__ wout,
    const float* __restrict__ bq, const float* __restrict__ bk,
    float* __restrict__ v, float* __restrict__ qconst)
{
  int tid = threadIdx.x;  // 0..511
  float a = 0.f, w = 0.f;
  #pragma unroll
  for (int j = 0; j < 16; ++j) {
    a += vpart[j * DD + tid];
    w += wpart[j * DD + tid];
  }
  v[tid] = a;

  __shared__ __align__(16) float w2s[DD];
  __shared__ float red[8];
  __shared__ float c0s;
  w2s[tid] = w;
  float cpart = wave_sum64(wout[tid] * (bq[tid] + bk[tid]));
  int wv = tid >> 6, ln = tid & 63;
  if (ln == 0) red[wv] = cpart;
  __syncthreads();
  if (tid == 0) {
    float c = 0.f;
    #pragma unroll
    for (int i = 0; i < 8; ++i) c += red[i];
    c0s = c;
  }
  __syncthreads();

  const float4* w24 = (const float4*)w2s;
  float4 x0 = w24[ln], x1 = w24[64 + ln];
  float c0 = c0s;
  #pragma unroll
  for (int t = 0; t < 2; ++t) {
    int b = wv * 2 + t;
    const float4* q4 = (const float4*)(query + (size_t)b * DD);
    float p = wave_sum64(dot8(q4[ln], q4[64 + ln], x0, x1));
    if (ln == 0) qconst[b] = p + c0;
  }
}

// K1: main streaming pass. grid = B*BPB blocks x 256 threads (4 waves).
// Each wave handles 4 consecutive rows per iteration (independent reduce
// chains), stride 16; prefetch next 4 rows one iteration ahead.
__global__ __launch_bounds__(256) void k_score(
    const float* __restrict__ key, const int* __restrict__ mask,
    const float* __restrict__ v, const float* __restrict__ qconst,
    float* __restrict__ scores, float* __restrict__ partials)
{
  int blk = blockIdx.x;
  int b = blk / BPB;
  int pb = blk % BPB;
  const int rows = SS / BPB;       // 128
  int s0 = pb * rows;
  int wave = threadIdx.x >> 6;
  int lane = threadIdx.x & 63;

  const float4* vv = (const float4*)v;
  float4 v0 = vv[lane], v1 = vv[64 + lane];
  float qc = qconst[b];
  const float4* keyb = (const float4*)(key + (size_t)b * SS * DD);
  const int* maskb = mask + b * SS;

  float m = -INFINITY, l = 0.f;
  float4 u0 = {0.f,0.f,0.f,0.f}, u1 = {0.f,0.f,0.f,0.f};

  const int nit = rows / 16;  // 8 iterations, 16 rows/block/iter
  int s = s0 + wave * 4;

  float4 r0a, r0b, r1a, r1b, r2a, r2b, r3a, r3b;
  {
    const float4* p0 = keyb + (size_t)s * (DD / 4);
    r0a = p0[lane];       r0b = p0[64 + lane];
    r1a = p0[128 + lane]; r1b = p0[192 + lane];
    r2a = p0[256 + lane]; r2b = p0[320 + lane];
    r3a = p0[384 + lane]; r3b = p0[448 + lane];
  }
  int4 mk = *(const int4*)(maskb + s);

  for (int i = 0; i < nit; ++i) {
    float4 n0a=r0a, n0b=r0b, n1a=r1a, n1b=r1b, n2a=r2a, n2b=r2b, n3a=r3a, n3b=r3b;
    int4 nmk = {0,0,0,0};
    if (i + 1 < nit) {
      const float4* p0 = keyb + (size_t)(s + 16) * (DD / 4);
      n0a = p0[lane];       n0b = p0[64 + lane];
      n1a = p0[128 + lane]; n1b = p0[192 + lane];
      n2a = p0[256 + lane]; n2b = p0[320 + lane];
      n3a = p0[384 + lane]; n3b = p0[448 + lane];
      nmk = *(const int4*)(maskb + s + 16);
    }
    float p0v = dot8(r0a, r0b, v0, v1);
    float p1v = dot8(r1a, r1b, v0, v1);
    float p2v = dot8(r2a, r2b, v0, v1);
    float p3v = dot8(r3a, r3b, v0, v1);
    #pragma unroll
    for (int off = 32; off; off >>= 1) {
      p0v += __shfl_xor(p0v, off, 64);
      p1v += __shfl_xor(p1v, off, 64);
      p2v += __shfl_xor(p2v, off, 64);
      p3v += __shfl_xor(p3v, off, 64);
    }
    float sc0 = mk.x ? NEG_INF : (p0v + qc);
    float sc1 = mk.y ? NEG_INF : (p1v + qc);
    float sc2 = mk.z ? NEG_INF : (p2v + qc);
    float sc3 = mk.w ? NEG_INF : (p3v + qc);
    if (lane == 0) {
      float4 st = {sc0, sc1, sc2, sc3};
      *(float4*)(scores + (size_t)b * SS + s) = st;
    }
    float mn = fmaxf(fmaxf(fmaxf(sc0, sc1), fmaxf(sc2, sc3)), m);
    if (mn > m) {  // wave-uniform
      float sc = __expf(m - mn);  // exp(-inf)=0 on first update
      l *= sc;
      u0.x *= sc; u0.y *= sc; u0.z *= sc; u0.w *= sc;
      u1.x *= sc; u1.y *= sc; u1.z *= sc; u1.w *= sc;
      m = mn;
    }
    float e0 = __expf(sc0 - m), e1 = __expf(sc1 - m);
    float e2 = __expf(sc2 - m), e3 = __expf(sc3 - m);
    l += (e0 + e1) + (e2 + e3);
    u0.x += e0*r0a.x + e1*r1a.x + e2*r2a.x + e3*r3a.x;
    u0.y += e0*r0a.y + e1*r1a.y + e2*r2a.y + e3*r3a.y;
    u0.z += e0*r0a.z + e1*r1a.z + e2*r2a.z + e3*r3a.z;
    u0.w += e0*r0a.w + e1*r1a.w + e2*r2a.w + e3*r3a.w;
    u1.x += e0*r0b.x + e1*r1b.x + e2*r2b.x + e3*r3b.x;
    u1.y += e0*r0b.y + e1*r1b.y + e2*r2b.y + e3*r3b.y;
    u1.z += e0*r0b.z + e1*r1b.z + e2*r2b.z + e3*r3b.z;
    u1.w += e0*r0b.w + e1*r1b.w + e2*r2b.w + e3*r3b.w;
    r0a=n0a; r0b=n0b; r1a=n1a; r1b=n1b; r2a=n2a; r2b=n2b; r3a=n3a; r3b=n3b;
    mk = nmk; s += 16;
  }

  // block combine across 4 waves
  __shared__ float ls_m[4], ls_l[4];
  __shared__ __align__(16) float ls_u[4][DD];
  ls_u[wave][4 * lane + 0] = u0.x; ls_u[wave][4 * lane + 1] = u0.y;
  ls_u[wave][4 * lane + 2] = u0.z; ls_u[wave][4 * lane + 3] = u0.w;
  ls_u[wave][256 + 4 * lane + 0] = u1.x; ls_u[wave][256 + 4 * lane + 1] = u1.y;
  ls_u[wave][256 + 4 * lane + 2] = u1.z; ls_u[wave][256 + 4 * lane + 3] = u1.w;
  if (lane == 0) { ls_m[wave] = m; ls_l[wave] = l; }
  __syncthreads();

  float M = fmaxf(fmaxf(ls_m[0], ls_m[1]), fmaxf(ls_m[2], ls_m[3]));
  float f0 = __expf(ls_m[0] - M), f1 = __expf(ls_m[1] - M);
  float f2 = __expf(ls_m[2] - M), f3 = __expf(ls_m[3] - M);
  int d = threadIdx.x;  // 0..255
  float ua = ls_u[0][d] * f0 + ls_u[1][d] * f1 + ls_u[2][d] * f2 + ls_u[3][d] * f3;
  float ub = ls_u[0][d + 256] * f0 + ls_u[1][d + 256] * f1
           + ls_u[2][d + 256] * f2 + ls_u[3][d + 256] * f3;
  float* part = partials + (size_t)(b * BPB + pb) * (DD + 2);
  part[2 + d] = ua;
  part[2 + 256 + d] = ub;
  if (threadIdx.x == 0) {
    part[0] = M;
    part[1] = ls_l[0] * f0 + ls_l[1] * f1 + ls_l[2] * f2 + ls_l[3] * f3;
  }
}

// K2a: 16 blocks x 256 threads. Combine partials -> normalized ubar[b][512].
__global__ __launch_bounds__(256) void k_comb(
    const float* __restrict__ partials, float* __restrict__ ubar)
{
  int b = blockIdx.x;
  int tid = threadIdx.x;
  __shared__ float fsh[BPB];
  __shared__ float dsh;
  const float* pbase = partials + (size_t)b * BPB * (DD + 2);

  if (tid < 64) {
    float mp = pbase[tid * (DD + 2)];
    float lp = pbase[tid * (DD + 2) + 1];
    float M = mp;
    #pragma unroll
    for (int off = 32; off; off >>= 1) M = fmaxf(M, __shfl_xor(M, off, 64));
    float f = __expf(mp - M);
    fsh[tid] = f;
    float dn = wave_sum64(lp * f);
    if (tid == 0) dsh = dn;
  }
  __syncthreads();

  float inv = 1.f / dsh;
  float ua = 0.f, ub_ = 0.f;
  #pragma unroll 8
  for (int p = 0; p < BPB; ++p) {
    float f = fsh[p];
    ua  += pbase[p * (DD + 2) + 2 + tid] * f;
    ub_ += pbase[p * (DD + 2) + 2 + 256 + tid] * f;
  }
  ubar[b * DD + tid] = ua * inv;
  ubar[b * DD + tid + 256] = ub_ * inv;
}

// K2b: 256 blocks (b, hc) x 256 threads. attn[b][h] = Wk[h].ubar[b] + bk[h],
// 32 h per block (8 wave-dots per wave). Wk served from L2/L3.
__global__ __launch_bounds__(256) void k_attn(
    const float* __restrict__ Wk, const float* __restrict__ bk,
    const float* __restrict__ ubar, float* __restrict__ attn)
{
  int b = blockIdx.x >> 4;
  int hc = blockIdx.x & 15;
  int wave = threadIdx.x >> 6, lane = threadIdx.x & 63;
  const float4* ub4 = (const float4*)(ubar + (size_t)b * DD);
  float4 x0 = ub4[lane], x1 = ub4[64 + lane];
  #pragma unroll
  for (int j = 0; j < 8; ++j) {
    int h = hc * 32 + wave * 8 + j;
    const float4* wr = (const float4*)(Wk + (size_t)h * DD);
    float p = wave_sum64(dot8(wr[lane], wr[64 + lane], x0, x1));
    if (lane == 0) attn[b * HH + h] = p + bk[h];
  }
}

extern "C" void kernel_launch(void* const* d_in, const int* in_sizes, int n_in,
                              void* d_out, int out_size, void* d_ws, size_t ws_size,
                              hipStream_t stream) {
  const float* query = (const float*)d_in[0];
  const float* key   = (const float*)d_in[1];
  const int*   mask  = (const int*)d_in[2];
  const float* Wq    = (const float*)d_in[3];
  const float* bq    = (const float*)d_in[4];
  const float* Wk    = (const float*)d_in[5];
  const float* bk    = (const float*)d_in[6];
  const float* wout  = (const float*)d_in[7];

  float* out    = (float*)d_out;
  float* attn   = out;                 // (B, H)
  float* scores = out + BB * HH;       // (B, S)
  float* ws     = (float*)d_ws;

  // ws layout (floats). scratch region is reused: vpart/wpart (k_gemv/k_fin)
  // then partials (k_score/k_comb) — stream order serializes the two uses.
  const size_t off_v    = 0;                    // 512
  const size_t off_qc   = 512;                  // 16
  const size_t off_ubar = 528;                  // 16*512
  const size_t off_scr  = off_ubar + BB * DD;   // max(2*16*512, B*BPB*(D+2))
  float* vpart    = ws + off_scr;
  float* wpart    = ws + off_scr + 16 * DD;
  float* partials = ws + off_scr;

  k_gemv<<<dim3(32), dim3(256), 0, stream>>>(Wq, Wk, wout, wpart, vpart);
  k_fin<<<dim3(1), dim3(512), 0, stream>>>(query, vpart, wpart, wout, bq, bk,
                                           ws + off_v, ws + off_qc);
  k_score<<<dim3(BB * BPB), dim3(256), 0, stream>>>(key, mask, ws + off_v, ws + off_qc,
                                                    scores, partials);
  k_comb<<<dim3(BB), dim3(256), 0, stream>>>(partials, ws + off_ubar);
  k_attn<<<dim3(BB * 16), dim3(256), 0, stream>>>(Wk, bk, ws + off_ubar, attn);
}

// Round 5
// 61.081 us; speedup vs baseline: 1.7234x; 1.1311x over previous
//
#include <hip/hip_runtime.h>
#include <math.h>

#define BB 16
#define SS 8192
#define DD 512
#define HH 512
#define NEG_INF (-1e18f)
#define BPB 64   // score-blocks per batch: 16*64 = 1024 blocks = 4 per CU

__device__ __forceinline__ float dot8(float4 a0, float4 a1, float4 b0, float4 b1) {
  return a0.x*b0.x + a0.y*b0.y + a0.z*b0.z + a0.w*b0.w
       + a1.x*b1.x + a1.y*b1.y + a1.z*b1.z + a1.w*b1.w;
}

// DPP wave64 sum: result valid in lane 63 only. VALU-only (no DS pipe).
template <int CTRL>
__device__ __forceinline__ float dpp_add0(float x) {
  return x + __int_as_float(__builtin_amdgcn_update_dpp(
      0, __float_as_int(x), CTRL, 0xf, 0xf, true));
}
__device__ __forceinline__ float wave_red_sum(float x) {
  x = dpp_add0<0x111>(x);  // row_shr:1
  x = dpp_add0<0x112>(x);  // row_shr:2
  x = dpp_add0<0x114>(x);  // row_shr:4
  x = dpp_add0<0x118>(x);  // row_shr:8
  x = dpp_add0<0x142>(x);  // row_bcast:15
  x = dpp_add0<0x143>(x);  // row_bcast:31
  return x;                // lane 63 = full sum
}
__device__ __forceinline__ float lane63(float x) {
  return __int_as_float(__builtin_amdgcn_readlane(__float_as_int(x), 63));
}
template <int CTRL>
__device__ __forceinline__ float dpp_maxstep(float x) {
  int y = __builtin_amdgcn_update_dpp(
      __float_as_int(x), __float_as_int(x), CTRL, 0xf, 0xf, false);
  return fmaxf(x, __int_as_float(y));
}
__device__ __forceinline__ float wave_red_max(float x) {
  x = dpp_maxstep<0x111>(x); x = dpp_maxstep<0x112>(x);
  x = dpp_maxstep<0x114>(x); x = dpp_maxstep<0x118>(x);
  x = dpp_maxstep<0x142>(x); x = dpp_maxstep<0x143>(x);
  return x;                // lane 63 = full max
}

// K0: 129 blocks x 256 threads, one launch, no stage-2 dependency.
// blocks [0,64):   v[j*8 .. j*8+8)  = sum_h wout[h]*Wk[h][slice]
// blocks [64,128): w2[j*8 .. j*8+8) = sum_h wout[h]*Wq[h][slice]
// block 128:       c0 = sum_h wout[h]*(bq[h]+bk[h])
__global__ __launch_bounds__(256) void k_prep(
    const float* __restrict__ Wq, const float* __restrict__ Wk,
    const float* __restrict__ wout, const float* __restrict__ bq,
    const float* __restrict__ bk, float* __restrict__ v,
    float* __restrict__ w2, float* __restrict__ c0)
{
  int blk = blockIdx.x;
  int t = threadIdx.x;
  if (blk == 128) {
    if (t < 64) {
      float part = 0.f;
      #pragma unroll
      for (int i = 0; i < 8; ++i) {
        int h = t + 64 * i;
        part += wout[h] * (bq[h] + bk[h]);
      }
      part = wave_red_sum(part);
      if (t == 63) c0[0] = part;
    }
    return;
  }
  int j = blk & 63;
  const float* W = (blk < 64) ? Wk : Wq;
  float* outp = (blk < 64) ? v : w2;
  int dsl = j * 8;
  int h0 = t, h1 = t + 256;
  const float4* r0 = (const float4*)(W + (size_t)h0 * DD + dsl);
  const float4* r1 = (const float4*)(W + (size_t)h1 * DD + dsl);
  float4 a0 = r0[0], a1 = r0[1], b0 = r1[0], b1 = r1[1];
  float wA = wout[h0], wB = wout[h1];
  float acc[8];
  acc[0] = wA*a0.x + wB*b0.x; acc[1] = wA*a0.y + wB*b0.y;
  acc[2] = wA*a0.z + wB*b0.z; acc[3] = wA*a0.w + wB*b0.w;
  acc[4] = wA*a1.x + wB*b1.x; acc[5] = wA*a1.y + wB*b1.y;
  acc[6] = wA*a1.z + wB*b1.z; acc[7] = wA*a1.w + wB*b1.w;
  __shared__ float red[256][9];
  #pragma unroll
  for (int k = 0; k < 8; ++k) red[t][k] = acc[k];
  __syncthreads();
  for (int st = 128; st; st >>= 1) {
    if (t < st) {
      #pragma unroll
      for (int k = 0; k < 8; ++k) red[t][k] += red[t + st][k];
    }
    __syncthreads();
  }
  if (t < 8) outp[dsl + t] = red[0][t];
}

// K1: main streaming pass. grid = B*BPB blocks x 256 threads (4 waves).
// 4 rows/wave/iter, depth-1 prefetch, DPP reductions, inline qc.
__global__ __launch_bounds__(256, 4) void k_score(
    const float* __restrict__ key, const int* __restrict__ mask,
    const float* __restrict__ query, const float* __restrict__ ws_v,
    const float* __restrict__ ws_w2, const float* __restrict__ ws_c0,
    float* __restrict__ scores, float* __restrict__ partials)
{
  int blk = blockIdx.x;
  int b = blk / BPB;
  int pb = blk % BPB;
  const int rows = SS / BPB;       // 128
  int s0 = pb * rows;
  int wave = threadIdx.x >> 6;
  int lane = threadIdx.x & 63;

  const float4* vv = (const float4*)ws_v;
  float4 v0 = vv[lane], v1 = vv[64 + lane];

  // qc = query[b].w2 + c0, computed redundantly per wave (L2-hot inputs)
  float qc;
  {
    const float4* q4 = (const float4*)(query + (size_t)b * DD);
    const float4* w24 = (const float4*)ws_w2;
    float qp = wave_red_sum(dot8(q4[lane], q4[64 + lane], w24[lane], w24[64 + lane]));
    qc = lane63(qp) + ws_c0[0];
  }

  const float4* keyb = (const float4*)(key + (size_t)b * SS * DD);
  const int* maskb = mask + b * SS;

  float m = -INFINITY, l = 0.f;
  float4 u0 = {0.f,0.f,0.f,0.f}, u1 = {0.f,0.f,0.f,0.f};

  const int nit = rows / 16;  // 8 iterations, 16 rows/block/iter
  int s = s0 + wave * 4;

  float4 r0a, r0b, r1a, r1b, r2a, r2b, r3a, r3b;
  {
    const float4* p0 = keyb + (size_t)s * (DD / 4);
    r0a = p0[lane];       r0b = p0[64 + lane];
    r1a = p0[128 + lane]; r1b = p0[192 + lane];
    r2a = p0[256 + lane]; r2b = p0[320 + lane];
    r3a = p0[384 + lane]; r3b = p0[448 + lane];
  }
  int4 mk = *(const int4*)(maskb + s);

  for (int i = 0; i < nit; ++i) {
    float4 n0a=r0a, n0b=r0b, n1a=r1a, n1b=r1b, n2a=r2a, n2b=r2b, n3a=r3a, n3b=r3b;
    int4 nmk = {0,0,0,0};
    if (i + 1 < nit) {
      const float4* p0 = keyb + (size_t)(s + 16) * (DD / 4);
      n0a = p0[lane];       n0b = p0[64 + lane];
      n1a = p0[128 + lane]; n1b = p0[192 + lane];
      n2a = p0[256 + lane]; n2b = p0[320 + lane];
      n3a = p0[384 + lane]; n3b = p0[448 + lane];
      nmk = *(const int4*)(maskb + s + 16);
    }
    // 4 independent DPP reduce chains (VALU only)
    float p0v = wave_red_sum(dot8(r0a, r0b, v0, v1));
    float p1v = wave_red_sum(dot8(r1a, r1b, v0, v1));
    float p2v = wave_red_sum(dot8(r2a, r2b, v0, v1));
    float p3v = wave_red_sum(dot8(r3a, r3b, v0, v1));
    float d0 = lane63(p0v), d1 = lane63(p1v);
    float d2 = lane63(p2v), d3 = lane63(p3v);
    float sc0 = mk.x ? NEG_INF : (d0 + qc);
    float sc1 = mk.y ? NEG_INF : (d1 + qc);
    float sc2 = mk.z ? NEG_INF : (d2 + qc);
    float sc3 = mk.w ? NEG_INF : (d3 + qc);
    if (lane == 0) {
      float4 st = {sc0, sc1, sc2, sc3};
      *(float4*)(scores + (size_t)b * SS + s) = st;
    }
    float mn = fmaxf(fmaxf(fmaxf(sc0, sc1), fmaxf(sc2, sc3)), m);
    if (mn > m) {  // wave-uniform
      float sc = __expf(m - mn);  // exp(-inf)=0 on first update
      l *= sc;
      u0.x *= sc; u0.y *= sc; u0.z *= sc; u0.w *= sc;
      u1.x *= sc; u1.y *= sc; u1.z *= sc; u1.w *= sc;
      m = mn;
    }
    float e0 = __expf(sc0 - m), e1 = __expf(sc1 - m);
    float e2 = __expf(sc2 - m), e3 = __expf(sc3 - m);
    l += (e0 + e1) + (e2 + e3);
    u0.x += e0*r0a.x + e1*r1a.x + e2*r2a.x + e3*r3a.x;
    u0.y += e0*r0a.y + e1*r1a.y + e2*r2a.y + e3*r3a.y;
    u0.z += e0*r0a.z + e1*r1a.z + e2*r2a.z + e3*r3a.z;
    u0.w += e0*r0a.w + e1*r1a.w + e2*r2a.w + e3*r3a.w;
    u1.x += e0*r0b.x + e1*r1b.x + e2*r2b.x + e3*r3b.x;
    u1.y += e0*r0b.y + e1*r1b.y + e2*r2b.y + e3*r3b.y;
    u1.z += e0*r0b.z + e1*r1b.z + e2*r2b.z + e3*r3b.z;
    u1.w += e0*r0b.w + e1*r1b.w + e2*r2b.w + e3*r3b.w;
    r0a=n0a; r0b=n0b; r1a=n1a; r1b=n1b; r2a=n2a; r2b=n2b; r3a=n3a; r3b=n3b;
    mk = nmk; s += 16;
  }

  // block combine across 4 waves
  __shared__ float ls_m[4], ls_l[4];
  __shared__ __align__(16) float ls_u[4][DD];
  ls_u[wave][4 * lane + 0] = u0.x; ls_u[wave][4 * lane + 1] = u0.y;
  ls_u[wave][4 * lane + 2] = u0.z; ls_u[wave][4 * lane + 3] = u0.w;
  ls_u[wave][256 + 4 * lane + 0] = u1.x; ls_u[wave][256 + 4 * lane + 1] = u1.y;
  ls_u[wave][256 + 4 * lane + 2] = u1.z; ls_u[wave][256 + 4 * lane + 3] = u1.w;
  if (lane == 0) { ls_m[wave] = m; ls_l[wave] = l; }
  __syncthreads();

  float M = fmaxf(fmaxf(ls_m[0], ls_m[1]), fmaxf(ls_m[2], ls_m[3]));
  float f0 = __expf(ls_m[0] - M), f1 = __expf(ls_m[1] - M);
  float f2 = __expf(ls_m[2] - M), f3 = __expf(ls_m[3] - M);
  int d = threadIdx.x;  // 0..255
  float ua = ls_u[0][d] * f0 + ls_u[1][d] * f1 + ls_u[2][d] * f2 + ls_u[3][d] * f3;
  float ub = ls_u[0][d + 256] * f0 + ls_u[1][d + 256] * f1
           + ls_u[2][d + 256] * f2 + ls_u[3][d + 256] * f3;
  float* part = partials + (size_t)(b * BPB + pb) * (DD + 2);
  part[2 + d] = ua;
  part[2 + 256 + d] = ub;
  if (threadIdx.x == 0) {
    part[0] = M;
    part[1] = ls_l[0] * f0 + ls_l[1] * f1 + ls_l[2] * f2 + ls_l[3] * f3;
  }
}

// K2: fused combine + attn. 256 blocks (b, hc) x 256 threads.
// Each block redundantly combines partials for its b (L2-resident), then
// computes 32 h-dots: attn[b][h] = Wk[h].ubar + bk[h].
__global__ __launch_bounds__(256) void k_out(
    const float* __restrict__ Wk, const float* __restrict__ bk,
    const float* __restrict__ partials, float* __restrict__ attn)
{
  int b = blockIdx.x >> 4;
  int hc = blockIdx.x & 15;
  int tid = threadIdx.x;
  int wave = tid >> 6, lane = tid & 63;
  __shared__ __align__(16) float ubar[DD];
  __shared__ float fsh[BPB];
  __shared__ float dsh;
  const float* pbase = partials + (size_t)b * BPB * (DD + 2);

  if (tid < 64) {
    float mp = pbase[tid * (DD + 2)];
    float lp = pbase[tid * (DD + 2) + 1];
    float M = lane63(wave_red_max(mp));
    float f = __expf(mp - M);
    fsh[tid] = f;
    float dn = wave_red_sum(lp * f);
    if (tid == 63) dsh = dn;
  }
  __syncthreads();

  float inv = 1.f / dsh;
  float ua = 0.f, ub_ = 0.f;
  #pragma unroll 8
  for (int p = 0; p < BPB; ++p) {
    float f = fsh[p];
    ua  += pbase[p * (DD + 2) + 2 + tid] * f;
    ub_ += pbase[p * (DD + 2) + 2 + 256 + tid] * f;
  }
  ubar[tid] = ua * inv;
  ubar[tid + 256] = ub_ * inv;
  __syncthreads();

  const float4* ub4 = (const float4*)ubar;
  float4 x0 = ub4[lane], x1 = ub4[64 + lane];
  #pragma unroll
  for (int j = 0; j < 8; ++j) {
    int h = hc * 32 + wave * 8 + j;
    const float4* wr = (const float4*)(Wk + (size_t)h * DD);
    float p = wave_red_sum(dot8(wr[lane], wr[64 + lane], x0, x1));
    if (lane == 63) attn[b * HH + h] = p + bk[h];
  }
}

extern "C" void kernel_launch(void* const* d_in, const int* in_sizes, int n_in,
                              void* d_out, int out_size, void* d_ws, size_t ws_size,
                              hipStream_t stream) {
  const float* query = (const float*)d_in[0];
  const float* key   = (const float*)d_in[1];
  const int*   mask  = (const int*)d_in[2];
  const float* Wq    = (const float*)d_in[3];
  const float* bq    = (const float*)d_in[4];
  const float* Wk    = (const float*)d_in[5];
  const float* bk    = (const float*)d_in[6];
  const float* wout  = (const float*)d_in[7];

  float* out    = (float*)d_out;
  float* attn   = out;                 // (B, H)
  float* scores = out + BB * HH;       // (B, S)
  float* ws     = (float*)d_ws;

  // ws layout (floats)
  float* ws_v  = ws;            // 512
  float* ws_w2 = ws + 512;      // 512
  float* ws_c0 = ws + 1024;     // 1 (pad to 1040)
  float* partials = ws + 1040;  // B*BPB*(D+2) ~ 2.06 MB

  k_prep<<<dim3(129), dim3(256), 0, stream>>>(Wq, Wk, wout, bq, bk,
                                              ws_v, ws_w2, ws_c0);
  k_score<<<dim3(BB * BPB), dim3(256), 0, stream>>>(key, mask, query, ws_v,
                                                    ws_w2, ws_c0, scores, partials);
  k_out<<<dim3(BB * 16), dim3(256), 0, stream>>>(Wk, bk, partials, attn);
}